// Round 1
// baseline (464.320 us; speedup 1.0000x reference)
//
#include <hip/hip_runtime.h>
#include <hip/hip_bf16.h>

#define D_ 1024
#define B_ 4
#define S_ 4096

typedef __attribute__((ext_vector_type(8))) short bf16x8;
typedef __attribute__((ext_vector_type(4))) float f32x4;
typedef __attribute__((ext_vector_type(4))) unsigned int u32x4;
typedef __attribute__((ext_vector_type(4))) unsigned short u16x4;

#define BM 128
#define BN 128
#define BK 64
#define NTHR 256

__device__ __forceinline__ unsigned short f2bf(float f) {
    // round-to-nearest-even f32 -> bf16 (no NaN handling needed here)
    unsigned int u = __builtin_bit_cast(unsigned int, f);
    u = u + 0x7fffu + ((u >> 16) & 1u);
    return (unsigned short)(u >> 16);
}
__device__ __forceinline__ unsigned int pk2(float a, float b) {
    return (unsigned int)f2bf(a) | ((unsigned int)f2bf(b) << 16);
}

// Stage a [128 rows][64 cols] tile (rows stride K elems in global) into LDS as
// bf16 with XOR swizzle: byte ^= (row&7)<<4  (guide G4: fixes the 128B-row-stride
// 32-way bank conflict; write and read use the same involution).
template<bool F32>
__device__ __forceinline__ void stage_tile(char* ldst, const void* gbase, int K, int kt, int tid) {
    const int srow = tid >> 3;   // 0..31
    const int sch  = tid & 7;    // 16B chunk within 128B row
#pragma unroll
    for (int p = 0; p < 4; ++p) {
        int row = p * 32 + srow;
        size_t goff = (size_t)row * K + kt + sch * 8;
        u32x4 val;
        if constexpr (F32) {
            const float* g = (const float*)gbase;
            f32x4 v0 = *(const f32x4*)(g + goff);
            f32x4 v1 = *(const f32x4*)(g + goff + 4);
            val[0] = pk2(v0[0], v0[1]);
            val[1] = pk2(v0[2], v0[3]);
            val[2] = pk2(v1[0], v1[1]);
            val[3] = pk2(v1[2], v1[3]);
        } else {
            const unsigned short* g = (const unsigned short*)gbase;
            val = *(const u32x4*)(g + goff);
        }
        int byt = row * 128 + sch * 16;
        byt ^= (row & 7) << 4;
        *(u32x4*)(ldst + byt) = val;
    }
}

// NT GEMM: A [M,K] row-major (K contig), B [N,K] row-major, C[m,n] = sum_k A*B.
// Batched via blockIdx.z with element strides sA/sB/sO.
// TRANS=1 stores output transposed: Op[z*sO + n*M + m].
template<bool A_F32, bool B_F32, bool OUT_F32, bool TRANS, bool RELU>
__global__ __launch_bounds__(NTHR)
void gemm_nt(const void* __restrict__ Ap, const void* __restrict__ Bp,
             void* __restrict__ Op, int M, int N, int K,
             long long sA, long long sB, long long sO)
{
    __shared__ char lds[2 * BM * BK * 2];   // 16KB A + 16KB B
    char* lds_a = lds;
    char* lds_b = lds + BM * BK * 2;

    const int tid = threadIdx.x;
    const int bz  = blockIdx.z;
    const int bm  = blockIdx.y * BM;
    const int bn  = blockIdx.x * BN;

    const void* Abase;
    const void* Bbase;
    if constexpr (A_F32) Abase = (const void*)((const float*)Ap + (size_t)bz * sA + (size_t)bm * K);
    else                 Abase = (const void*)((const unsigned short*)Ap + (size_t)bz * sA + (size_t)bm * K);
    if constexpr (B_F32) Bbase = (const void*)((const float*)Bp + (size_t)bz * sB + (size_t)bn * K);
    else                 Bbase = (const void*)((const unsigned short*)Bp + (size_t)bz * sB + (size_t)bn * K);

    const int lane = tid & 63;
    const int wave = tid >> 6;
    const int wm   = (wave >> 1) * 64;   // 2x2 wave grid, 64x64 per wave
    const int wn   = (wave & 1) * 64;
    const int l16  = lane & 15;
    const int lhi  = lane >> 4;

    f32x4 acc[4][4];
#pragma unroll
    for (int i = 0; i < 4; ++i)
#pragma unroll
        for (int j = 0; j < 4; ++j)
            acc[i][j] = (f32x4){0.f, 0.f, 0.f, 0.f};

    for (int kt = 0; kt < K; kt += BK) {
        stage_tile<A_F32>(lds_a, Abase, K, kt, tid);
        stage_tile<B_F32>(lds_b, Bbase, K, kt, tid);
        __syncthreads();
#pragma unroll
        for (int kk = 0; kk < BK / 32; ++kk) {
            bf16x8 af[4], bfr[4];
#pragma unroll
            for (int i = 0; i < 4; ++i) {
                int row = wm + i * 16 + l16;
                int byt = row * 128 + kk * 64 + lhi * 16;
                byt ^= (row & 7) << 4;
                af[i] = *(const bf16x8*)(lds_a + byt);
            }
#pragma unroll
            for (int j = 0; j < 4; ++j) {
                int row = wn + j * 16 + l16;
                int byt = row * 128 + kk * 64 + lhi * 16;
                byt ^= (row & 7) << 4;
                bfr[j] = *(const bf16x8*)(lds_b + byt);
            }
#pragma unroll
            for (int i = 0; i < 4; ++i)
#pragma unroll
                for (int j = 0; j < 4; ++j)
                    acc[i][j] = __builtin_amdgcn_mfma_f32_16x16x32_bf16(af[i], bfr[j], acc[i][j], 0, 0, 0);
        }
        __syncthreads();
    }

    // C/D layout (guide-verified m89/m91): col = lane&15, row = (lane>>4)*4 + reg
    const size_t obase = (size_t)bz * (size_t)sO;
    if constexpr (!TRANS) {
#pragma unroll
        for (int i = 0; i < 4; ++i) {
            const int m0 = bm + wm + i * 16 + lhi * 4;
#pragma unroll
            for (int j = 0; j < 4; ++j) {
                const int n = bn + wn + j * 16 + l16;
#pragma unroll
                for (int r = 0; r < 4; ++r) {
                    float v = acc[i][j][r];
                    if constexpr (RELU) v = fmaxf(v, 0.f);
                    size_t addr = obase + (size_t)(m0 + r) * N + n;
                    if constexpr (OUT_F32) ((float*)Op)[addr] = v;
                    else ((unsigned short*)Op)[addr] = f2bf(v);
                }
            }
        }
    } else {
#pragma unroll
        for (int i = 0; i < 4; ++i) {
            const int m0 = bm + wm + i * 16 + lhi * 4;   // multiple of 4 -> 8B aligned
#pragma unroll
            for (int j = 0; j < 4; ++j) {
                const int n = bn + wn + j * 16 + l16;
                u16x4 h;
#pragma unroll
                for (int r = 0; r < 4; ++r) {
                    float v = acc[i][j][r];
                    if constexpr (RELU) v = fmaxf(v, 0.f);
                    h[r] = f2bf(v);
                }
                *(u16x4*)((unsigned short*)Op + obase + (size_t)n * M + m0) = h;
            }
        }
    }
}

extern "C" void kernel_launch(void* const* d_in, const int* in_sizes, int n_in,
                              void* d_out, int out_size, void* d_ws, size_t ws_size,
                              hipStream_t stream) {
    (void)in_sizes; (void)n_in; (void)out_size; (void)ws_size;
    const float* x  = (const float*)d_in[0];
    const float* Wa = (const float*)d_in[1];
    const float* Wb = (const float*)d_in[2];
    const float* Wc = (const float*)d_in[3];
    const float* Wd = (const float*)d_in[4];

    // ws: two 33.55MB bf16 regions, reused. E (8.4MB bf16) parks in d_out
    // (fully overwritten by the final GEMM each call -> deterministic).
    unsigned short* r0 = (unsigned short*)d_ws;
    unsigned short* r1 = (unsigned short*)((char*)d_ws + (size_t)33554432);
    unsigned short* Et = (unsigned short*)d_out;

    const long long SD  = (long long)S_ * D_;   // per-batch [S,D] elems
    const long long DD2 = (long long)D_ * D_;   // per-batch [D,D] elems

    dim3 blk(NTHR, 1, 1);
    dim3 gS(D_ / BN, S_ / BM, B_);   // (8,32,4)  M=4096 per batch
    dim3 gD(D_ / BN, D_ / BM, B_);   // (8,8,4)   M=1024 per batch

    // 1) Bmt[b][e][s] = relu(x Wb^T)^T      (transposed store)
    gemm_nt<true,  true,  false, true,  true ><<<gS, blk, 0, stream>>>(x,  Wb, r0, S_, D_, D_, SD, 0, SD);
    // 2) Ct[b][e][s]  = relu(x Wc^T)^T
    gemm_nt<true,  true,  false, true,  true ><<<gS, blk, 0, stream>>>(x,  Wc, r1, S_, D_, D_, SD, 0, SD);
    // 3) Et[b][e][d1] = (Bmt @ Ct^T)^T  ==  E[d1][e] transposed   (K=S=4096)
    gemm_nt<false, false, false, true,  false><<<gD, blk, 0, stream>>>(r0, r1, Et, D_, D_, S_, SD, SD, DD2);
    // 4) A[b][s][d1]  = relu(x Wa^T)     -> r0 (Bmt dead)
    gemm_nt<true,  true,  false, false, true ><<<gS, blk, 0, stream>>>(x,  Wa, r0, S_, D_, D_, SD, 0, SD);
    // 5) O[b][s][e]   = A @ E            -> r1 (Ct dead)
    gemm_nt<false, false, false, false, false><<<gS, blk, 0, stream>>>(r0, Et, r1, S_, D_, D_, SD, DD2, SD);
    // 6) out = relu(O Wd^T)  f32         -> d_out (overwrites Et scratch)
    gemm_nt<false, true,  true,  false, true ><<<gS, blk, 0, stream>>>(r1, Wd, (float*)d_out, S_, D_, D_, SD, 0, SD);
}

// Round 2
// 390.290 us; speedup vs baseline: 1.1897x; 1.1897x over previous
//
#include <hip/hip_runtime.h>
#include <hip/hip_bf16.h>

#define D_ 1024
#define B_ 4
#define S_ 4096

typedef __attribute__((ext_vector_type(8))) short bf16x8;
typedef __attribute__((ext_vector_type(4))) float f32x4;
typedef __attribute__((ext_vector_type(4))) unsigned int u32x4;
typedef __attribute__((ext_vector_type(4))) unsigned short u16x4;

#define BM 128
#define BN 128
#define BK 64
#define NTHR 256

__device__ __forceinline__ unsigned short f2bf(float f) {
    unsigned int u = __builtin_bit_cast(unsigned int, f);
    u = u + 0x7fffu + ((u >> 16) & 1u);
    return (unsigned short)(u >> 16);
}
__device__ __forceinline__ unsigned int pk2(float a, float b) {
    return (unsigned int)f2bf(a) | ((unsigned int)f2bf(b) << 16);
}

__device__ __forceinline__ void gload16(const void* g, void* l) {
    __builtin_amdgcn_global_load_lds(
        (const __attribute__((address_space(1))) void*)g,
        (__attribute__((address_space(3))) void*)l, 16, 0, 0);
}

// f32 -> bf16 elementwise convert, 8 elems/thread/iter
__global__ __launch_bounds__(256)
void conv_bf16(const float* __restrict__ src, unsigned short* __restrict__ dst, int n8) {
    int i = blockIdx.x * blockDim.x + threadIdx.x;
    const int stride = gridDim.x * blockDim.x;
    for (; i < n8; i += stride) {
        f32x4 v0 = *(const f32x4*)(src + (size_t)i * 8);
        f32x4 v1 = *(const f32x4*)(src + (size_t)i * 8 + 4);
        u32x4 o;
        o[0] = pk2(v0[0], v0[1]);
        o[1] = pk2(v0[2], v0[3]);
        o[2] = pk2(v1[0], v1[1]);
        o[3] = pk2(v1[2], v1[3]);
        *(u32x4*)(dst + (size_t)i * 8) = o;
    }
}

// Reg-staged f32->bf16 tile stage (only for step-6 conservative Wd path).
// Writes the SAME swizzled physical layout as the gload16 path.
__device__ __forceinline__ void stage_tile_f32(char* ldst, const float* g, int K, int kt, int tid) {
    const int srow = tid >> 3;
    const int sch  = tid & 7;
#pragma unroll
    for (int p = 0; p < 4; ++p) {
        int row = p * 32 + srow;
        size_t goff = (size_t)row * K + kt + sch * 8;
        f32x4 v0 = *(const f32x4*)(g + goff);
        f32x4 v1 = *(const f32x4*)(g + goff + 4);
        u32x4 val;
        val[0] = pk2(v0[0], v0[1]);
        val[1] = pk2(v0[2], v0[3]);
        val[2] = pk2(v1[0], v1[1]);
        val[3] = pk2(v1[2], v1[3]);
        int byt = row * 128 + sch * 16;
        byt ^= (row & 7) << 4;
        *(u32x4*)(ldst + byt) = val;
    }
}

// NT GEMM: A [M,K] bf16 row-major, B [N,K] row-major (bf16 unless B_F32),
// C[m,n] = sum_k A[m,k]*B[n,k]. Batched via blockIdx.z (elem strides sA/sB/sO).
// TRANS=1 stores transposed: Op[z*sO + n*M + m].
// Staging: global_load_lds dwordx4, linear LDS dest, pre-swizzled global src
// (rule #21: same involution on source permutation and read XOR).
template<bool B_F32, bool OUT_F32, bool TRANS, bool RELU>
__global__ __launch_bounds__(NTHR)
void gemm_nt(const unsigned short* __restrict__ Ap, const void* __restrict__ Bp,
             void* __restrict__ Op, int M, int N, int K,
             long long sA, long long sB, long long sO)
{
    __shared__ char lds_a[BM * BK * 2];   // 16KB
    __shared__ char lds_b[BN * BK * 2];   // 16KB

    const int tid = threadIdx.x;
    const int bz  = blockIdx.z;
    const int bm  = blockIdx.y * BM;
    const int bn  = blockIdx.x * BN;

    const unsigned short* Abase = Ap + (size_t)bz * sA + (size_t)bm * K;
    const unsigned short* Bb16 = nullptr;
    const float*          Bf32 = nullptr;
    if constexpr (B_F32) Bf32 = (const float*)Bp + (size_t)bz * sB + (size_t)bn * K;
    else                 Bb16 = (const unsigned short*)Bp + (size_t)bz * sB + (size_t)bn * K;

    const int lane = tid & 63;
    const int wave = tid >> 6;
    const int wm   = (wave >> 1) * 64;
    const int wn   = (wave & 1) * 64;
    const int l16  = lane & 15;
    const int lhi  = lane >> 4;

    // staging geometry: lane writes physical chunk (lane&7) of row
    // r = wave*32 + p*8 + (lane>>3); r&7 == lane>>3, so the logical chunk this
    // lane must FETCH is c = (lane&7) ^ (lane>>3)  (constant per lane).
    const int srow0 = wave * 32 + (lane >> 3);
    const int schnk = (lane & 7) ^ (lane >> 3);
    const char* gA0 = (const char*)(Abase + (size_t)srow0 * K) + schnk * 16;
    const char* gB0 = nullptr;
    if constexpr (!B_F32) gB0 = (const char*)(Bb16 + (size_t)srow0 * K) + schnk * 16;
    char* lA0 = lds_a + wave * 4096;
    char* lB0 = lds_b + wave * 4096;

    f32x4 acc[4][4];
#pragma unroll
    for (int i = 0; i < 4; ++i)
#pragma unroll
        for (int j = 0; j < 4; ++j)
            acc[i][j] = (f32x4){0.f, 0.f, 0.f, 0.f};

    for (int kt = 0; kt < K; kt += BK) {
#pragma unroll
        for (int p = 0; p < 4; ++p)
            gload16(gA0 + ((size_t)p * 8 * K + kt) * 2, lA0 + p * 1024);
        if constexpr (!B_F32) {
#pragma unroll
            for (int p = 0; p < 4; ++p)
                gload16(gB0 + ((size_t)p * 8 * K + kt) * 2, lB0 + p * 1024);
        } else {
            stage_tile_f32(lds_b, Bf32, K, kt, tid);
        }
        __syncthreads();
#pragma unroll
        for (int kk = 0; kk < BK / 32; ++kk) {
            bf16x8 af[4], bfr[4];
#pragma unroll
            for (int i = 0; i < 4; ++i) {
                int row = wm + i * 16 + l16;
                int byt = row * 128 + kk * 64 + lhi * 16;
                byt ^= (row & 7) << 4;
                af[i] = *(const bf16x8*)(lds_a + byt);
            }
#pragma unroll
            for (int j = 0; j < 4; ++j) {
                int row = wn + j * 16 + l16;
                int byt = row * 128 + kk * 64 + lhi * 16;
                byt ^= (row & 7) << 4;
                bfr[j] = *(const bf16x8*)(lds_b + byt);
            }
#pragma unroll
            for (int i = 0; i < 4; ++i)
#pragma unroll
                for (int j = 0; j < 4; ++j)
                    acc[i][j] = __builtin_amdgcn_mfma_f32_16x16x32_bf16(af[i], bfr[j], acc[i][j], 0, 0, 0);
        }
        __syncthreads();
    }

    // C/D layout: col = lane&15, row = (lane>>4)*4 + reg
    const size_t obase = (size_t)bz * (size_t)sO;
    if constexpr (!TRANS) {
#pragma unroll
        for (int i = 0; i < 4; ++i) {
            const int m0 = bm + wm + i * 16 + lhi * 4;
#pragma unroll
            for (int j = 0; j < 4; ++j) {
                const int n = bn + wn + j * 16 + l16;
#pragma unroll
                for (int r = 0; r < 4; ++r) {
                    float v = acc[i][j][r];
                    if constexpr (RELU) v = fmaxf(v, 0.f);
                    size_t addr = obase + (size_t)(m0 + r) * N + n;
                    if constexpr (OUT_F32) ((float*)Op)[addr] = v;
                    else ((unsigned short*)Op)[addr] = f2bf(v);
                }
            }
        }
    } else {
#pragma unroll
        for (int i = 0; i < 4; ++i) {
            const int m0 = bm + wm + i * 16 + lhi * 4;
#pragma unroll
            for (int j = 0; j < 4; ++j) {
                const int n = bn + wn + j * 16 + l16;
                u16x4 h;
#pragma unroll
                for (int r = 0; r < 4; ++r) {
                    float v = acc[i][j][r];
                    if constexpr (RELU) v = fmaxf(v, 0.f);
                    h[r] = f2bf(v);
                }
                *(u16x4*)((unsigned short*)Op + obase + (size_t)n * M + m0) = h;
            }
        }
    }
}

extern "C" void kernel_launch(void* const* d_in, const int* in_sizes, int n_in,
                              void* d_out, int out_size, void* d_ws, size_t ws_size,
                              hipStream_t stream) {
    (void)in_sizes; (void)n_in; (void)out_size;
    const float* x  = (const float*)d_in[0];
    const float* Wa = (const float*)d_in[1];
    const float* Wb = (const float*)d_in[2];
    const float* Wc = (const float*)d_in[3];
    const float* Wd = (const float*)d_in[4];

    const long long SD  = (long long)S_ * D_;
    const long long DD2 = (long long)D_ * D_;

    // ws: r0 (32MB) + r1 (32MB). If ws is big enough, Et + Wdb also go in ws
    // (all-bf16 step 6); otherwise Et parks in d_out and step 6 reg-stages Wd f32.
    unsigned short* r0 = (unsigned short*)d_ws;
    unsigned short* r1 = (unsigned short*)((char*)d_ws + (size_t)32 * 1024 * 1024);
    const bool big_ws = ws_size >= (size_t)76 * 1024 * 1024;

    // d_out scratch (all dead before step 6 overwrites d_out with f32 result):
    // xb @0 (32MB), Et @32MB (8MB), Wab @40MB, Wbb @42MB, Wcb @44MB
    char* ob = (char*)d_out;
    unsigned short* xb  = (unsigned short*)ob;
    unsigned short* Et  = big_ws ? (unsigned short*)((char*)d_ws + (size_t)64 * 1024 * 1024)
                                 : (unsigned short*)(ob + (size_t)32 * 1024 * 1024);
    unsigned short* Wab = (unsigned short*)(ob + (size_t)40 * 1024 * 1024);
    unsigned short* Wbb = (unsigned short*)(ob + (size_t)42 * 1024 * 1024);
    unsigned short* Wcb = (unsigned short*)(ob + (size_t)44 * 1024 * 1024);
    unsigned short* Wdb = big_ws ? (unsigned short*)((char*)d_ws + (size_t)72 * 1024 * 1024) : nullptr;

    dim3 blk(NTHR, 1, 1);
    dim3 gS(D_ / BN, S_ / BM, B_);   // (8,32,4)
    dim3 gD(D_ / BN, D_ / BM, B_);   // (8,8,4)

    // 0) bf16-ify inputs
    conv_bf16<<<2048, blk, 0, stream>>>(x,  xb,  (B_ * S_ * D_) / 8);
    conv_bf16<<<512,  blk, 0, stream>>>(Wa, Wab, (D_ * D_) / 8);
    conv_bf16<<<512,  blk, 0, stream>>>(Wb, Wbb, (D_ * D_) / 8);
    conv_bf16<<<512,  blk, 0, stream>>>(Wc, Wcb, (D_ * D_) / 8);
    if (big_ws)
        conv_bf16<<<512, blk, 0, stream>>>(Wd, Wdb, (D_ * D_) / 8);

    // 1) Bmt[b][e][s] = relu(xb Wb^T)^T
    gemm_nt<false, false, true,  true ><<<gS, blk, 0, stream>>>(xb, Wbb, r0, S_, D_, D_, SD, 0, SD);
    // 2) Ct[b][e][s]  = relu(xb Wc^T)^T
    gemm_nt<false, false, true,  true ><<<gS, blk, 0, stream>>>(xb, Wcb, r1, S_, D_, D_, SD, 0, SD);
    // 3) Et[e'][e] = E2[e][e'] = sum_s Bm[s,e] C[s,e']   (K=S=4096, transposed store)
    gemm_nt<false, false, true,  false><<<gD, blk, 0, stream>>>(r0, r1, Et, D_, D_, S_, SD, SD, DD2);
    // 4) A[b][s][e] = relu(xb Wa^T)   -> r0 (Bmt dead)
    gemm_nt<false, false, false, true ><<<gS, blk, 0, stream>>>(xb, Wab, r0, S_, D_, D_, SD, 0, SD);
    // 5) O[b][s][e'] = A @ E2         -> r1 (Ct dead)
    gemm_nt<false, false, false, false><<<gS, blk, 0, stream>>>(r0, Et, r1, S_, D_, D_, SD, DD2, SD);
    // 6) out = relu(O Wd^T) f32       -> d_out (overwrites all d_out scratch)
    if (big_ws)
        gemm_nt<false, true, false, true ><<<gS, blk, 0, stream>>>(r1, Wdb, (float*)d_out, S_, D_, D_, SD, 0, SD);
    else
        gemm_nt<true,  true, false, true ><<<gS, blk, 0, stream>>>(r1, Wd,  (float*)d_out, S_, D_, D_, SD, 0, SD);
}

// Round 3
// 336.252 us; speedup vs baseline: 1.3809x; 1.1607x over previous
//
#include <hip/hip_runtime.h>
#include <hip/hip_bf16.h>

#define D_ 1024
#define B_ 4
#define S_ 4096

typedef __attribute__((ext_vector_type(8))) short bf16x8;
typedef __attribute__((ext_vector_type(4))) float f32x4;
typedef __attribute__((ext_vector_type(4))) unsigned int u32x4;
typedef __attribute__((ext_vector_type(4))) unsigned short u16x4;

#define BM 128
#define BN 128
#define BK 64
#define NTHR 256

__device__ __forceinline__ unsigned short f2bf(float f) {
    unsigned int u = __builtin_bit_cast(unsigned int, f);
    u = u + 0x7fffu + ((u >> 16) & 1u);
    return (unsigned short)(u >> 16);
}
__device__ __forceinline__ unsigned int pk2(float a, float b) {
    return (unsigned int)f2bf(a) | ((unsigned int)f2bf(b) << 16);
}
__device__ __forceinline__ float bf2f(unsigned short h) {
    unsigned int u = ((unsigned int)h) << 16;
    return __builtin_bit_cast(float, u);
}

__device__ __forceinline__ void gload16(const void* g, void* l) {
    __builtin_amdgcn_global_load_lds(
        (const __attribute__((address_space(1))) void*)g,
        (__attribute__((address_space(3))) void*)l, 16, 0, 0);
}

// f32 -> bf16 elementwise convert, 8 elems/thread/iter
__global__ __launch_bounds__(256)
void conv_bf16(const float* __restrict__ src, unsigned short* __restrict__ dst, int n8) {
    int i = blockIdx.x * blockDim.x + threadIdx.x;
    const int stride = gridDim.x * blockDim.x;
    for (; i < n8; i += stride) {
        f32x4 v0 = *(const f32x4*)(src + (size_t)i * 8);
        f32x4 v1 = *(const f32x4*)(src + (size_t)i * 8 + 4);
        u32x4 o;
        o[0] = pk2(v0[0], v0[1]);
        o[1] = pk2(v0[2], v0[3]);
        o[2] = pk2(v1[0], v1[1]);
        o[3] = pk2(v1[2], v1[3]);
        *(u32x4*)(dst + (size_t)i * 8) = o;
    }
}

// Enorm[b][i] = P[2b][i] + P[2b+1][i]   (bf16 in, f32 add, bf16 out)
__global__ __launch_bounds__(256)
void reduce2_bf16(const unsigned short* __restrict__ P, unsigned short* __restrict__ E, int n8_total) {
    int t = blockIdx.x * blockDim.x + threadIdx.x;
    const int stride = gridDim.x * blockDim.x;
    const int DD = D_ * D_;
    for (; t < n8_total; t += stride) {
        size_t idx = (size_t)t * 8;
        int b = (int)(idx / DD);
        size_t i = idx % DD;
        const unsigned short* p0 = P + (size_t)(2 * b) * DD + i;
        const unsigned short* p1 = P + (size_t)(2 * b + 1) * DD + i;
        u16x4 a0 = *(const u16x4*)p0;
        u16x4 a1 = *(const u16x4*)(p0 + 4);
        u16x4 b0 = *(const u16x4*)p1;
        u16x4 b1 = *(const u16x4*)(p1 + 4);
        u16x4 o0, o1;
#pragma unroll
        for (int k = 0; k < 4; ++k) {
            o0[k] = f2bf(bf2f(a0[k]) + bf2f(b0[k]));
            o1[k] = f2bf(bf2f(a1[k]) + bf2f(b1[k]));
        }
        *(u16x4*)(E + idx) = o0;
        *(u16x4*)(E + idx + 4) = o1;
    }
}

// NT GEMM, all-bf16 inputs: A [.,K] row-major, B [.,K] row-major,
// C[m,n] = sum_k A[m,k]*B[n,k].
// Batching/split-K: batch = bz/split, k-range = [(bz%split)*klen, +klen).
// Output indexed by bz (so split>1 writes per-half partials): Op + bz*sO.
// TRANS=1 stores Op[bz*sO + n*M + m].
// Staging: global_load_lds dwordx4, linear LDS dest, pre-swizzled global src;
// reads XOR byte ^= (row&7)<<4 (same involution).
template<bool OUT_F32, bool TRANS, bool RELU>
__global__ __launch_bounds__(NTHR)
void gemm_nt(const unsigned short* __restrict__ Ap, const unsigned short* __restrict__ Bp,
             void* __restrict__ Op, int M, int N, int K, int klen, int split,
             long long sA, long long sB, long long sO)
{
    __shared__ char lds_a[BM * BK * 2];   // 16KB
    __shared__ char lds_b[BN * BK * 2];   // 16KB

    const int tid   = threadIdx.x;
    const int bz    = blockIdx.z;
    const int batch = bz / split;
    const int k0    = (bz % split) * klen;
    const int bm    = blockIdx.y * BM;
    const int bn    = blockIdx.x * BN;

    const unsigned short* Abase = Ap + (size_t)batch * sA + (size_t)bm * K;
    const unsigned short* Bbase = Bp + (size_t)batch * sB + (size_t)bn * K;

    const int lane = tid & 63;
    const int wave = tid >> 6;
    const int wm   = (wave >> 1) * 64;
    const int wn   = (wave & 1) * 64;
    const int l16  = lane & 15;
    const int lhi  = lane >> 4;

    // staging geometry: lane writes physical chunk (lane&7) of row
    // r = wave*32 + p*8 + (lane>>3); logical chunk fetched = (lane&7)^(lane>>3).
    const int srow0 = wave * 32 + (lane >> 3);
    const int schnk = (lane & 7) ^ (lane >> 3);
    const char* gA0 = (const char*)(Abase + (size_t)srow0 * K) + schnk * 16;
    const char* gB0 = (const char*)(Bbase + (size_t)srow0 * K) + schnk * 16;
    char* lA0 = lds_a + wave * 4096;
    char* lB0 = lds_b + wave * 4096;

    f32x4 acc[4][4];
#pragma unroll
    for (int i = 0; i < 4; ++i)
#pragma unroll
        for (int j = 0; j < 4; ++j)
            acc[i][j] = (f32x4){0.f, 0.f, 0.f, 0.f};

    for (int kt = k0; kt < k0 + klen; kt += BK) {
#pragma unroll
        for (int p = 0; p < 4; ++p)
            gload16(gA0 + ((size_t)p * 8 * K + kt) * 2, lA0 + p * 1024);
#pragma unroll
        for (int p = 0; p < 4; ++p)
            gload16(gB0 + ((size_t)p * 8 * K + kt) * 2, lB0 + p * 1024);
        __syncthreads();
#pragma unroll
        for (int kk = 0; kk < BK / 32; ++kk) {
            bf16x8 af[4], bfr[4];
#pragma unroll
            for (int i = 0; i < 4; ++i) {
                int row = wm + i * 16 + l16;
                int byt = row * 128 + kk * 64 + lhi * 16;
                byt ^= (row & 7) << 4;
                af[i] = *(const bf16x8*)(lds_a + byt);
            }
#pragma unroll
            for (int j = 0; j < 4; ++j) {
                int row = wn + j * 16 + l16;
                int byt = row * 128 + kk * 64 + lhi * 16;
                byt ^= (row & 7) << 4;
                bfr[j] = *(const bf16x8*)(lds_b + byt);
            }
#pragma unroll
            for (int i = 0; i < 4; ++i)
#pragma unroll
                for (int j = 0; j < 4; ++j)
                    acc[i][j] = __builtin_amdgcn_mfma_f32_16x16x32_bf16(af[i], bfr[j], acc[i][j], 0, 0, 0);
        }
        __syncthreads();
    }

    // C/D layout: col = lane&15, row = (lane>>4)*4 + reg
    const size_t obase = (size_t)bz * (size_t)sO;
    if constexpr (!TRANS) {
#pragma unroll
        for (int i = 0; i < 4; ++i) {
            const int m0 = bm + wm + i * 16 + lhi * 4;
#pragma unroll
            for (int j = 0; j < 4; ++j) {
                const int n = bn + wn + j * 16 + l16;
#pragma unroll
                for (int r = 0; r < 4; ++r) {
                    float v = acc[i][j][r];
                    if constexpr (RELU) v = fmaxf(v, 0.f);
                    size_t addr = obase + (size_t)(m0 + r) * N + n;
                    if constexpr (OUT_F32) ((float*)Op)[addr] = v;
                    else ((unsigned short*)Op)[addr] = f2bf(v);
                }
            }
        }
    } else {
#pragma unroll
        for (int i = 0; i < 4; ++i) {
            const int m0 = bm + wm + i * 16 + lhi * 4;
#pragma unroll
            for (int j = 0; j < 4; ++j) {
                const int n = bn + wn + j * 16 + l16;
                u16x4 h;
#pragma unroll
                for (int r = 0; r < 4; ++r) {
                    float v = acc[i][j][r];
                    if constexpr (RELU) v = fmaxf(v, 0.f);
                    h[r] = f2bf(v);
                }
                *(u16x4*)((unsigned short*)Op + obase + (size_t)n * M + m0) = h;
            }
        }
    }
}

extern "C" void kernel_launch(void* const* d_in, const int* in_sizes, int n_in,
                              void* d_out, int out_size, void* d_ws, size_t ws_size,
                              hipStream_t stream) {
    (void)in_sizes; (void)n_in; (void)out_size; (void)ws_size;
    const float* x  = (const float*)d_in[0];
    const float* Wa = (const float*)d_in[1];
    const float* Wb = (const float*)d_in[2];
    const float* Wc = (const float*)d_in[3];
    const float* Wd = (const float*)d_in[4];

    const long long SD  = (long long)S_ * D_;   // [S,D] per-batch elems
    const long long DD2 = (long long)D_ * D_;   // [D,D] per-batch elems
    const size_t MB = 1024 * 1024;

    // ws (>=64MB, proven in r1/r2): r0 @0 (32MB), r1 @32MB (32MB).
    // Ft (8MB) reuses r1 after Ct is dead.
    unsigned short* r0 = (unsigned short*)d_ws;
    unsigned short* r1 = (unsigned short*)((char*)d_ws + 32 * MB);
    unsigned short* Ft = r1;

    // d_out scratch (64MB, all dead before the final GEMM overwrites it):
    // xb@0 (32MB) | P partials @32MB (16MB, overwrites dead Wbb/Wcb)
    // Enorm @48MB (8MB) | Wab @56MB | Wdb @58MB
    char* ob = (char*)d_out;
    unsigned short* xb    = (unsigned short*)ob;
    unsigned short* Wbb   = (unsigned short*)(ob + 32 * MB);
    unsigned short* Wcb   = (unsigned short*)(ob + 34 * MB);
    unsigned short* Pp    = (unsigned short*)(ob + 32 * MB);   // [8][D][D] bf16
    unsigned short* Enorm = (unsigned short*)(ob + 48 * MB);   // [B][D][D] bf16
    unsigned short* Wab   = (unsigned short*)(ob + 56 * MB);
    unsigned short* Wdb   = (unsigned short*)(ob + 58 * MB);

    dim3 blk(NTHR, 1, 1);
    dim3 gS(D_ / BN, S_ / BM, B_);       // (8,32,4)  S-GEMMs
    dim3 gE(D_ / BN, D_ / BM, B_ * 2);   // (8,8,8)   split-K=2 E-GEMM
    dim3 gD(D_ / BN, D_ / BM, B_);       // (8,8,4)   F-GEMM

    // 0) bf16-ify inputs (Wab/Wdb parked high in d_out, untouched until final)
    conv_bf16<<<2048, blk, 0, stream>>>(x,  xb,  (B_ * S_ * D_) / 8);
    conv_bf16<<<512,  blk, 0, stream>>>(Wb, Wbb, (D_ * D_) / 8);
    conv_bf16<<<512,  blk, 0, stream>>>(Wc, Wcb, (D_ * D_) / 8);
    conv_bf16<<<512,  blk, 0, stream>>>(Wa, Wab, (D_ * D_) / 8);
    conv_bf16<<<512,  blk, 0, stream>>>(Wd, Wdb, (D_ * D_) / 8);

    // 1) Bmt[b][e][s] = relu(xb Wb^T)^T  -> r0
    gemm_nt<false, true,  true ><<<gS, blk, 0, stream>>>(xb, Wbb, r0, S_, D_, D_, D_, 1, SD, 0, SD);
    // 2) Ct[b][e][s]  = relu(xb Wc^T)^T  -> r1
    gemm_nt<false, true,  true ><<<gS, blk, 0, stream>>>(xb, Wcb, r1, S_, D_, D_, D_, 1, SD, 0, SD);
    // 3) E2 partials: P[b*2+h][e][e'] = sum_{s in half h} Bm[s,e] C[s,e']
    gemm_nt<false, false, false><<<gE, blk, 0, stream>>>(r0, r1, Pp, D_, D_, S_, S_ / 2, 2, SD, SD, DD2);
    // 3b) Enorm[b] = P[2b] + P[2b+1]
    reduce2_bf16<<<2048, blk, 0, stream>>>(Pp, Enorm, (B_ * D_ * D_) / 8);
    // 3c) Ft[b][dout][e] = (E2[b] @ Wd^T)^T   (K=D, tiny)
    gemm_nt<false, true,  false><<<gD, blk, 0, stream>>>(Enorm, Wdb, Ft, D_, D_, D_, D_, 1, DD2, 0, DD2);
    // 4) A[b][s][e] = relu(xb Wa^T)  -> r0 (Bmt dead)
    gemm_nt<false, false, true ><<<gS, blk, 0, stream>>>(xb, Wab, r0, S_, D_, D_, D_, 1, SD, 0, SD);
    // 5) out = relu(A @ F) f32 -> d_out (reads only ws; overwrites all d_out scratch)
    gemm_nt<true,  false, true ><<<gS, blk, 0, stream>>>(r0, Ft, (float*)d_out, S_, D_, D_, D_, 1, SD, DD2, SD);
}

// Round 4
// 261.028 us; speedup vs baseline: 1.7788x; 1.2882x over previous
//
#include <hip/hip_runtime.h>
#include <hip/hip_bf16.h>

#define D_ 1024
#define B_ 4
#define S_ 4096

typedef __attribute__((ext_vector_type(8))) short bf16x8;
typedef __attribute__((ext_vector_type(4))) float f32x4;
typedef __attribute__((ext_vector_type(4))) unsigned int u32x4;
typedef __attribute__((ext_vector_type(4))) unsigned short u16x4;

__device__ __forceinline__ unsigned short f2bf(float f) {
    unsigned int u = __builtin_bit_cast(unsigned int, f);
    u = u + 0x7fffu + ((u >> 16) & 1u);
    return (unsigned short)(u >> 16);
}
__device__ __forceinline__ unsigned int pk2(float a, float b) {
    return (unsigned int)f2bf(a) | ((unsigned int)f2bf(b) << 16);
}
__device__ __forceinline__ float bf2f(unsigned short h) {
    unsigned int u = ((unsigned int)h) << 16;
    return __builtin_bit_cast(float, u);
}
__device__ __forceinline__ void gload16(const void* g, void* l) {
    __builtin_amdgcn_global_load_lds(
        (const __attribute__((address_space(1))) void*)g,
        (__attribute__((address_space(3))) void*)l, 16, 0, 0);
}

// ---------------- elementwise helpers ----------------
__global__ __launch_bounds__(256)
void conv_bf16(const float* __restrict__ src, unsigned short* __restrict__ dst, int n8) {
    int i = blockIdx.x * blockDim.x + threadIdx.x;
    const int stride = gridDim.x * blockDim.x;
    for (; i < n8; i += stride) {
        f32x4 v0 = *(const f32x4*)(src + (size_t)i * 8);
        f32x4 v1 = *(const f32x4*)(src + (size_t)i * 8 + 4);
        u32x4 o;
        o[0] = pk2(v0[0], v0[1]);
        o[1] = pk2(v0[2], v0[3]);
        o[2] = pk2(v1[0], v1[1]);
        o[3] = pk2(v1[2], v1[3]);
        *(u32x4*)(dst + (size_t)i * 8) = o;
    }
}

// E[b][i] = sum_seg P[b*split+seg][i]
__global__ __launch_bounds__(256)
void reduceN_bf16(const unsigned short* __restrict__ P, unsigned short* __restrict__ E,
                  int split, int n8_total) {
    int t = blockIdx.x * blockDim.x + threadIdx.x;
    const int stride = gridDim.x * blockDim.x;
    const int DD = D_ * D_;
    for (; t < n8_total; t += stride) {
        size_t idx = (size_t)t * 8;
        int b = (int)(idx / DD);
        size_t i = idx % DD;
        float s[8];
#pragma unroll
        for (int k = 0; k < 8; ++k) s[k] = 0.f;
        for (int seg = 0; seg < split; ++seg) {
            const unsigned short* p = P + (size_t)(b * split + seg) * DD + i;
            u16x4 v0 = *(const u16x4*)p;
            u16x4 v1 = *(const u16x4*)(p + 4);
#pragma unroll
            for (int k = 0; k < 4; ++k) { s[k] += bf2f(v0[k]); s[4 + k] += bf2f(v1[k]); }
        }
        u16x4 o0, o1;
#pragma unroll
        for (int k = 0; k < 4; ++k) { o0[k] = f2bf(s[k]); o1[k] = f2bf(s[4 + k]); }
        *(u16x4*)(E + idx) = o0;
        *(u16x4*)(E + idx + 4) = o1;
    }
}

// ---------------- 128x128 2-phase kernel (proven; used for small F-GEMM) ----------------
#define BM 128
#define BN 128
#define BK 64
#define NTHR 256

template<bool OUT_F32, bool TRANS, bool RELU>
__global__ __launch_bounds__(NTHR)
void gemm_nt(const unsigned short* __restrict__ Ap, const unsigned short* __restrict__ Bp,
             void* __restrict__ Op, int M, int N, int K, int klen, int split,
             long long sA, long long sB, long long sO)
{
    __shared__ char lds_a[BM * BK * 2];
    __shared__ char lds_b[BN * BK * 2];

    const int tid   = threadIdx.x;
    const int bz    = blockIdx.z;
    const int batch = bz / split;
    const int k0    = (bz % split) * klen;
    const int bm    = blockIdx.y * BM;
    const int bn    = blockIdx.x * BN;

    const unsigned short* Abase = Ap + (size_t)batch * sA + (size_t)bm * K;
    const unsigned short* Bbase = Bp + (size_t)batch * sB + (size_t)bn * K;

    const int lane = tid & 63;
    const int wave = tid >> 6;
    const int wm   = (wave >> 1) * 64;
    const int wn   = (wave & 1) * 64;
    const int l16  = lane & 15;
    const int lhi  = lane >> 4;

    const int srow0 = wave * 32 + (lane >> 3);
    const int schnk = (lane & 7) ^ (lane >> 3);
    const char* gA0 = (const char*)(Abase + (size_t)srow0 * K) + schnk * 16;
    const char* gB0 = (const char*)(Bbase + (size_t)srow0 * K) + schnk * 16;
    char* lA0 = lds_a + wave * 4096;
    char* lB0 = lds_b + wave * 4096;

    f32x4 acc[4][4];
#pragma unroll
    for (int i = 0; i < 4; ++i)
#pragma unroll
        for (int j = 0; j < 4; ++j)
            acc[i][j] = (f32x4){0.f, 0.f, 0.f, 0.f};

    for (int kt = k0; kt < k0 + klen; kt += BK) {
#pragma unroll
        for (int p = 0; p < 4; ++p)
            gload16(gA0 + ((size_t)p * 8 * K + kt) * 2, lA0 + p * 1024);
#pragma unroll
        for (int p = 0; p < 4; ++p)
            gload16(gB0 + ((size_t)p * 8 * K + kt) * 2, lB0 + p * 1024);
        __syncthreads();
#pragma unroll
        for (int kk = 0; kk < BK / 32; ++kk) {
            bf16x8 af[4], bfr[4];
#pragma unroll
            for (int i = 0; i < 4; ++i) {
                int row = wm + i * 16 + l16;
                int byt = (row * 128 + kk * 64 + lhi * 16) ^ ((row & 7) << 4);
                af[i] = *(const bf16x8*)(lds_a + byt);
            }
#pragma unroll
            for (int j = 0; j < 4; ++j) {
                int row = wn + j * 16 + l16;
                int byt = (row * 128 + kk * 64 + lhi * 16) ^ ((row & 7) << 4);
                bfr[j] = *(const bf16x8*)(lds_b + byt);
            }
#pragma unroll
            for (int i = 0; i < 4; ++i)
#pragma unroll
                for (int j = 0; j < 4; ++j)
                    acc[i][j] = __builtin_amdgcn_mfma_f32_16x16x32_bf16(af[i], bfr[j], acc[i][j], 0, 0, 0);
        }
        __syncthreads();
    }

    const size_t obase = (size_t)bz * (size_t)sO;
    if constexpr (!TRANS) {
#pragma unroll
        for (int i = 0; i < 4; ++i) {
            const int m0 = bm + wm + i * 16 + lhi * 4;
#pragma unroll
            for (int j = 0; j < 4; ++j) {
                const int n = bn + wn + j * 16 + l16;
#pragma unroll
                for (int r = 0; r < 4; ++r) {
                    float v = acc[i][j][r];
                    if constexpr (RELU) v = fmaxf(v, 0.f);
                    size_t addr = obase + (size_t)(m0 + r) * N + n;
                    if constexpr (OUT_F32) ((float*)Op)[addr] = v;
                    else ((unsigned short*)Op)[addr] = f2bf(v);
                }
            }
        }
    } else {
#pragma unroll
        for (int i = 0; i < 4; ++i) {
            const int m0 = bm + wm + i * 16 + lhi * 4;
#pragma unroll
            for (int j = 0; j < 4; ++j) {
                const int n = bn + wn + j * 16 + l16;
                u16x4 h;
#pragma unroll
                for (int r = 0; r < 4; ++r) {
                    float v = acc[i][j][r];
                    if constexpr (RELU) v = fmaxf(v, 0.f);
                    h[r] = f2bf(v);
                }
                *(u16x4*)((unsigned short*)Op + obase + (size_t)n * M + m0) = h;
            }
        }
    }
}

// ---------------- 256x256 8-phase kernel (T1+T2+T3+T4+T5) ----------------
// BMxBN=256x256, BK=64, 512 thr = 8 waves (2M x 4N), per-wave out 128x64.
// LDS 128KB: buf c at c*65536 { A-tile @0 (256x64 bf16, row r @ r*128B),
// B-tile @32768 }. Swizzle involution on reads: byte ^= (row&7)<<4; staging
// keeps LDS linear and pre-swizzles the per-lane GLOBAL chunk (rule #21).
// Schedule per iteration (tiles t0=2i in buf0, t1=2i+1 in buf1), 8 phases:
//   ph1: ldA(0,mh0) ldB(0,nh0) | stage B(buf1,t1)   | bar lgkm0 mm(0,0) bar
//   ph2: ldB(0,nh1)                                 | bar lgkm0 mm(0,1) bar
//   ph3: ldA(0,mh1) ldB(0,nh0)                      | bar lgkm0 mm(1,0) bar
//   ph4: ldB(0,nh1) | stage A(buf0,t0+2)            | bar lgkm0 mm(1,1) vmcnt(4) bar
//   ph5..ph8: same on buf1, staging B(buf0,t0+2) at ph5, A(buf1,t1+2) at ph8,
//   vmcnt(4) at ph8.
// Region-free proof: each stage slot follows the phase containing the region's
// last ds_read; every phase ends lgkmcnt(0)-then-barrier, so all waves' reads
// landed before any wave issues the overwriting stage. vmcnt(4) gates leave
// exactly the newest 4 loads (one stage slot) outstanding - staged data is
// resident >=1 gate+barrier before it is ds_read. Prefetch wraps (t%NT) write
// only already-consumed regions: benign.
#define CTILE 65536
#define CBOFF 32768

template<bool OUT_F32, bool TRANS, bool RELU>
__global__ __launch_bounds__(512, 2)
void gemm256(const unsigned short* __restrict__ Ap, const unsigned short* __restrict__ Bp,
             void* __restrict__ Op, int M, int N, int K, int klen, int split,
             long long sA, long long sB, long long sO)
{
    __shared__ char lds[131072];
    const int tid  = threadIdx.x;
    const int wave = tid >> 6;
    const int lane = tid & 63;

    // XCD-aware bijective block swizzle (all grids have nwg % 8 == 0)
    const int gx = gridDim.x, gy = gridDim.y;
    const int f   = blockIdx.x + gx * (blockIdx.y + gy * blockIdx.z);
    const int nwg = gx * gy * (int)gridDim.z;
    const int s   = (f & 7) * (nwg >> 3) + (f >> 3);
    const int lx  = s % gx;
    const int lyz = s / gx;
    const int ly  = lyz % gy;
    const int lz  = lyz / gy;

    const int batch = lz / split;
    const int k0    = (lz % split) * klen;
    const int bm    = ly * 256;
    const int bn    = lx * 256;

    const int wm  = (wave >> 2) * 128;
    const int wn  = (wave & 3) * 64;
    const int l16 = lane & 15, lhi = lane >> 4;

    const unsigned short* Abase = Ap + (size_t)batch * sA + (size_t)bm * K;
    const unsigned short* Bbase = Bp + (size_t)batch * sB + (size_t)bn * K;
    const int srow  = lane >> 3;              // row-within-8 this lane stages
    const int schnk = (lane & 7) ^ srow;      // pre-swizzled global 16B chunk
    const size_t K2 = (size_t)K * 2;
    const char* gA = (const char*)Abase + (size_t)srow * K2 + (size_t)schnk * 16 + (size_t)k0 * 2;
    const char* gB = (const char*)Bbase + (size_t)srow * K2 + (size_t)schnk * 16 + (size_t)k0 * 2;

    f32x4 acc[8][4];
#pragma unroll
    for (int i = 0; i < 8; ++i)
#pragma unroll
        for (int j = 0; j < 4; ++j)
            acc[i][j] = (f32x4){0.f, 0.f, 0.f, 0.f};

    bf16x8 a[4][2], b[2][2];

    auto stageA = [&](int c, int t) {   // both A halves of tile t -> buf c (4 loads)
#pragma unroll
        for (int h = 0; h < 2; ++h)
#pragma unroll
            for (int p = 0; p < 2; ++p)
                gload16(gA + (size_t)t * 128 + (size_t)(h * 128 + wave * 16 + p * 8) * K2,
                        lds + c * CTILE + h * 16384 + wave * 2048 + p * 1024);
    };
    auto stageB = [&](int c, int t) {
#pragma unroll
        for (int h = 0; h < 2; ++h)
#pragma unroll
            for (int p = 0; p < 2; ++p)
                gload16(gB + (size_t)t * 128 + (size_t)(h * 128 + wave * 16 + p * 8) * K2,
                        lds + c * CTILE + CBOFF + h * 16384 + wave * 2048 + p * 1024);
    };
    auto ldA = [&](int c, int mh) {
#pragma unroll
        for (int i4 = 0; i4 < 4; ++i4)
#pragma unroll
            for (int kk = 0; kk < 2; ++kk) {
                int row = wm + mh * 64 + i4 * 16 + l16;
                int byt = (row * 128 + kk * 64 + lhi * 16) ^ ((row & 7) << 4);
                a[i4][kk] = *(const bf16x8*)(lds + c * CTILE + byt);
            }
    };
    auto ldB = [&](int c, int nh) {
#pragma unroll
        for (int j2 = 0; j2 < 2; ++j2)
#pragma unroll
            for (int kk = 0; kk < 2; ++kk) {
                int row = wn + nh * 32 + j2 * 16 + l16;
                int byt = (row * 128 + kk * 64 + lhi * 16) ^ ((row & 7) << 4);
                b[j2][kk] = *(const bf16x8*)(lds + c * CTILE + CBOFF + byt);
            }
    };
    auto mm = [&](int mh, int nh) {
        __builtin_amdgcn_s_setprio(1);
#pragma unroll
        for (int i4 = 0; i4 < 4; ++i4)
#pragma unroll
            for (int j2 = 0; j2 < 2; ++j2)
#pragma unroll
                for (int kk = 0; kk < 2; ++kk)
                    acc[mh * 4 + i4][nh * 2 + j2] = __builtin_amdgcn_mfma_f32_16x16x32_bf16(
                        a[i4][kk], b[j2][kk], acc[mh * 4 + i4][nh * 2 + j2], 0, 0, 0);
        __builtin_amdgcn_s_setprio(0);
    };

#define BAR()  __builtin_amdgcn_s_barrier()
#define LGKM0() asm volatile("s_waitcnt lgkmcnt(0)" ::: "memory")
#define VM4()  asm volatile("s_waitcnt vmcnt(4)" ::: "memory")

    const int NT = klen / 64;
    // prologue: tile0 (A+B) -> buf0, tile1 A -> buf1; wait tile0, leave A(b1,1) in flight
    stageA(0, 0); stageB(0, 0); stageA(1, 1);
    VM4();
    BAR();

    for (int itr = 0; itr < NT / 2; ++itr) {
        const int t1  = 2 * itr + 1;
        const int tp0 = (2 * itr + 2) % NT;
        const int tp1 = (2 * itr + 3) % NT;
        // ph1
        ldA(0, 0); ldB(0, 0); stageB(1, t1);
        BAR(); LGKM0(); mm(0, 0); BAR();
        // ph2
        ldB(0, 1);
        BAR(); LGKM0(); mm(0, 1); BAR();
        // ph3
        ldA(0, 1); ldB(0, 0);
        BAR(); LGKM0(); mm(1, 0); BAR();
        // ph4
        ldB(0, 1); stageA(0, tp0);
        BAR(); LGKM0(); mm(1, 1); VM4(); BAR();
        // ph5
        ldA(1, 0); ldB(1, 0); stageB(0, tp0);
        BAR(); LGKM0(); mm(0, 0); BAR();
        // ph6
        ldB(1, 1);
        BAR(); LGKM0(); mm(0, 1); BAR();
        // ph7
        ldA(1, 1); ldB(1, 0);
        BAR(); LGKM0(); mm(1, 0); BAR();
        // ph8
        ldB(1, 1); stageA(1, tp1);
        BAR(); LGKM0(); mm(1, 1); VM4(); BAR();
    }
    asm volatile("s_waitcnt vmcnt(0)" ::: "memory");   // drain LDS-DMA before end

    // epilogue: C/D layout col=lane&15, row=(lane>>4)*4+reg
    const size_t obase = (size_t)lz * (size_t)sO;
    if constexpr (!TRANS) {
#pragma unroll
        for (int i = 0; i < 8; ++i) {
            const int m0 = bm + wm + i * 16 + lhi * 4;
#pragma unroll
            for (int j = 0; j < 4; ++j) {
                const int n = bn + wn + j * 16 + l16;
#pragma unroll
                for (int r = 0; r < 4; ++r) {
                    float v = acc[i][j][r];
                    if constexpr (RELU) v = fmaxf(v, 0.f);
                    size_t addr = obase + (size_t)(m0 + r) * N + n;
                    if constexpr (OUT_F32) ((float*)Op)[addr] = v;
                    else ((unsigned short*)Op)[addr] = f2bf(v);
                }
            }
        }
    } else {
#pragma unroll
        for (int i = 0; i < 8; ++i) {
            const int m0 = bm + wm + i * 16 + lhi * 4;
#pragma unroll
            for (int j = 0; j < 4; ++j) {
                const int n = bn + wn + j * 16 + l16;
                u16x4 h;
#pragma unroll
                for (int r = 0; r < 4; ++r) {
                    float v = acc[i][j][r];
                    if constexpr (RELU) v = fmaxf(v, 0.f);
                    h[r] = f2bf(v);
                }
                *(u16x4*)((unsigned short*)Op + obase + (size_t)n * M + m0) = h;
            }
        }
    }
#undef BAR
#undef LGKM0
#undef VM4
}

extern "C" void kernel_launch(void* const* d_in, const int* in_sizes, int n_in,
                              void* d_out, int out_size, void* d_ws, size_t ws_size,
                              hipStream_t stream) {
    (void)in_sizes; (void)n_in; (void)out_size;
    const float* x  = (const float*)d_in[0];
    const float* Wa = (const float*)d_in[1];
    const float* Wb = (const float*)d_in[2];
    const float* Wc = (const float*)d_in[3];
    const float* Wd = (const float*)d_in[4];

    const long long SD  = (long long)S_ * D_;
    const long long DD2 = (long long)D_ * D_;
    const size_t MB = 1024 * 1024;

    // ws: r0 @0 (32MB), r1 @32MB (32MB); if ws >= 96MB, E-partials P @64MB (32MB, split4)
    unsigned short* r0 = (unsigned short*)d_ws;
    unsigned short* r1 = (unsigned short*)((char*)d_ws + 32 * MB);
    unsigned short* Ft = r1;                      // 8MB, reuses Ct region after E
    const bool big_ws = ws_size >= (size_t)96 * MB;

    // d_out scratch (64MB, all dead before final GEMM overwrites):
    // xb@0-32 | P(small path)@32-48 | Enorm@48-56 | Wbb@56 Wcb@58 Wab@60 Wdb@62
    char* ob = (char*)d_out;
    unsigned short* xb    = (unsigned short*)ob;
    unsigned short* Pp    = big_ws ? (unsigned short*)((char*)d_ws + 64 * MB)
                                   : (unsigned short*)(ob + 32 * MB);
    unsigned short* Enorm = (unsigned short*)(ob + 48 * MB);
    unsigned short* Wbb   = (unsigned short*)(ob + 56 * MB);
    unsigned short* Wcb   = (unsigned short*)(ob + 58 * MB);
    unsigned short* Wab   = (unsigned short*)(ob + 60 * MB);
    unsigned short* Wdb   = (unsigned short*)(ob + 62 * MB);
    const int esplit = big_ws ? 4 : 2;
    const int eklen  = S_ / esplit;

    dim3 blk256(256, 1, 1);
    dim3 blk512(512, 1, 1);
    dim3 gS(D_ / 256, S_ / 256, B_);          // (4,16,4) = 256 blocks
    dim3 gE(D_ / 256, D_ / 256, B_ * esplit); // (4,4,16) or (4,4,8)
    dim3 gF(D_ / BN, D_ / BM, B_);            // (8,8,4) old kernel

    // 0) bf16-ify inputs
    conv_bf16<<<2048, blk256, 0, stream>>>(x,  xb,  (B_ * S_ * D_) / 8);
    conv_bf16<<<512,  blk256, 0, stream>>>(Wb, Wbb, (D_ * D_) / 8);
    conv_bf16<<<512,  blk256, 0, stream>>>(Wc, Wcb, (D_ * D_) / 8);
    conv_bf16<<<512,  blk256, 0, stream>>>(Wa, Wab, (D_ * D_) / 8);
    conv_bf16<<<512,  blk256, 0, stream>>>(Wd, Wdb, (D_ * D_) / 8);

    // 1) Bmt[b][e][s] = relu(xb Wb^T)^T  -> r0
    gemm256<false, true,  true ><<<gS, blk512, 0, stream>>>(xb, Wbb, r0, S_, D_, D_, D_, 1, SD, 0, SD);
    // 2) Ct[b][e][s]  = relu(xb Wc^T)^T  -> r1
    gemm256<false, true,  true ><<<gS, blk512, 0, stream>>>(xb, Wcb, r1, S_, D_, D_, D_, 1, SD, 0, SD);
    // 3) E2 partials: P[b*split+seg][e][e'] = sum_{s in seg} Bm[s,e] C[s,e']
    gemm256<false, false, false><<<gE, blk512, 0, stream>>>(r0, r1, Pp, D_, D_, S_, eklen, esplit, SD, SD, DD2);
    // 3b) Enorm[b] = sum_seg P
    reduceN_bf16<<<2048, blk256, 0, stream>>>(Pp, Enorm, esplit, (B_ * D_ * D_) / 8);
    // 3c) Ft[b][dout][e] = (E2 @ Wd^T)^T   (small: old 128^2 kernel) -> r1 (Ct dead)
    gemm_nt<false, true,  false><<<gF, blk256, 0, stream>>>(Enorm, Wdb, Ft, D_, D_, D_, D_, 1, DD2, 0, DD2);
    // 4) A[b][s][e] = relu(xb Wa^T) -> r0 (Bmt dead)
    gemm256<false, false, true ><<<gS, blk512, 0, stream>>>(xb, Wab, r0, S_, D_, D_, D_, 1, SD, 0, SD);
    // 5) out = relu(A @ Ft^T-rows) f32 -> d_out (reads only ws; overwrites d_out scratch)
    gemm256<true,  false, true ><<<gS, blk512, 0, stream>>>(r0, Ft, (float*)d_out, S_, D_, D_, D_, 1, SD, DD2, SD);
}

// Round 5
// 250.547 us; speedup vs baseline: 1.8532x; 1.0418x over previous
//
#include <hip/hip_runtime.h>
#include <hip/hip_bf16.h>

#define D_ 1024
#define B_ 4
#define S_ 4096

typedef __attribute__((ext_vector_type(8))) short bf16x8;
typedef __attribute__((ext_vector_type(4))) float f32x4;
typedef __attribute__((ext_vector_type(4))) unsigned int u32x4;
typedef __attribute__((ext_vector_type(4))) unsigned short u16x4;

__device__ __forceinline__ unsigned short f2bf(float f) {
    unsigned int u = __builtin_bit_cast(unsigned int, f);
    u = u + 0x7fffu + ((u >> 16) & 1u);
    return (unsigned short)(u >> 16);
}
__device__ __forceinline__ unsigned int pk2(float a, float b) {
    return (unsigned int)f2bf(a) | ((unsigned int)f2bf(b) << 16);
}
__device__ __forceinline__ float bf2f(unsigned short h) {
    unsigned int u = ((unsigned int)h) << 16;
    return __builtin_bit_cast(float, u);
}
__device__ __forceinline__ void gload16(const void* g, void* l) {
    __builtin_amdgcn_global_load_lds(
        (const __attribute__((address_space(1))) void*)g,
        (__attribute__((address_space(3))) void*)l, 16, 0, 0);
}

// ---------------- elementwise helpers ----------------
__global__ __launch_bounds__(256)
void conv_bf16(const float* __restrict__ src, unsigned short* __restrict__ dst, int n8) {
    int i = blockIdx.x * blockDim.x + threadIdx.x;
    const int stride = gridDim.x * blockDim.x;
    for (; i < n8; i += stride) {
        f32x4 v0 = *(const f32x4*)(src + (size_t)i * 8);
        f32x4 v1 = *(const f32x4*)(src + (size_t)i * 8 + 4);
        u32x4 o;
        o[0] = pk2(v0[0], v0[1]);
        o[1] = pk2(v0[2], v0[3]);
        o[2] = pk2(v1[0], v1[1]);
        o[3] = pk2(v1[2], v1[3]);
        *(u32x4*)(dst + (size_t)i * 8) = o;
    }
}

// convert 4 same-size f32 arrays -> bf16 in one launch
__global__ __launch_bounds__(256)
void conv_bf16_w4(const float* __restrict__ s0, const float* __restrict__ s1,
                  const float* __restrict__ s2, const float* __restrict__ s3,
                  unsigned short* __restrict__ d0, unsigned short* __restrict__ d1,
                  unsigned short* __restrict__ d2, unsigned short* __restrict__ d3,
                  int n8_per) {
    int i = blockIdx.x * blockDim.x + threadIdx.x;
    const int stride = gridDim.x * blockDim.x;
    for (; i < 4 * n8_per; i += stride) {
        int w = i / n8_per;
        size_t j = (size_t)(i - w * n8_per) * 8;
        const float* s = (w == 0) ? s0 : (w == 1) ? s1 : (w == 2) ? s2 : s3;
        unsigned short* d = (w == 0) ? d0 : (w == 1) ? d1 : (w == 2) ? d2 : d3;
        f32x4 v0 = *(const f32x4*)(s + j);
        f32x4 v1 = *(const f32x4*)(s + j + 4);
        u32x4 o;
        o[0] = pk2(v0[0], v0[1]);
        o[1] = pk2(v0[2], v0[3]);
        o[2] = pk2(v1[0], v1[1]);
        o[3] = pk2(v1[2], v1[3]);
        *(u32x4*)(d + j) = o;
    }
}

// E[b][i] = sum_seg P[b*split+seg][i]
__global__ __launch_bounds__(256)
void reduceN_bf16(const unsigned short* __restrict__ P, unsigned short* __restrict__ E,
                  int split, int n8_total) {
    int t = blockIdx.x * blockDim.x + threadIdx.x;
    const int stride = gridDim.x * blockDim.x;
    const int DD = D_ * D_;
    for (; t < n8_total; t += stride) {
        size_t idx = (size_t)t * 8;
        int b = (int)(idx / DD);
        size_t i = idx % DD;
        float s[8];
#pragma unroll
        for (int k = 0; k < 8; ++k) s[k] = 0.f;
        for (int seg = 0; seg < split; ++seg) {
            const unsigned short* p = P + (size_t)(b * split + seg) * DD + i;
            u16x4 v0 = *(const u16x4*)p;
            u16x4 v1 = *(const u16x4*)(p + 4);
#pragma unroll
            for (int k = 0; k < 4; ++k) { s[k] += bf2f(v0[k]); s[4 + k] += bf2f(v1[k]); }
        }
        u16x4 o0, o1;
#pragma unroll
        for (int k = 0; k < 4; ++k) { o0[k] = f2bf(s[k]); o1[k] = f2bf(s[4 + k]); }
        *(u16x4*)(E + idx) = o0;
        *(u16x4*)(E + idx + 4) = o1;
    }
}

// ---------------- 128x128 2-phase kernel (proven; used for small F-GEMM) ----------------
#define BM 128
#define BN 128
#define BK 64
#define NTHR 256

template<bool OUT_F32, bool TRANS, bool RELU>
__global__ __launch_bounds__(NTHR)
void gemm_nt(const unsigned short* __restrict__ Ap, const unsigned short* __restrict__ Bp,
             void* __restrict__ Op, int M, int N, int K, int klen, int split,
             long long sA, long long sB, long long sO)
{
    __shared__ char lds_a[BM * BK * 2];
    __shared__ char lds_b[BN * BK * 2];

    const int tid   = threadIdx.x;
    const int bz    = blockIdx.z;
    const int batch = bz / split;
    const int k0    = (bz % split) * klen;
    const int bm    = blockIdx.y * BM;
    const int bn    = blockIdx.x * BN;

    const unsigned short* Abase = Ap + (size_t)batch * sA + (size_t)bm * K;
    const unsigned short* Bbase = Bp + (size_t)batch * sB + (size_t)bn * K;

    const int lane = tid & 63;
    const int wave = tid >> 6;
    const int wm   = (wave >> 1) * 64;
    const int wn   = (wave & 1) * 64;
    const int l16  = lane & 15;
    const int lhi  = lane >> 4;

    const int srow0 = wave * 32 + (lane >> 3);
    const int schnk = (lane & 7) ^ (lane >> 3);
    const char* gA0 = (const char*)(Abase + (size_t)srow0 * K) + schnk * 16;
    const char* gB0 = (const char*)(Bbase + (size_t)srow0 * K) + schnk * 16;
    char* lA0 = lds_a + wave * 4096;
    char* lB0 = lds_b + wave * 4096;

    f32x4 acc[4][4];
#pragma unroll
    for (int i = 0; i < 4; ++i)
#pragma unroll
        for (int j = 0; j < 4; ++j)
            acc[i][j] = (f32x4){0.f, 0.f, 0.f, 0.f};

    for (int kt = k0; kt < k0 + klen; kt += BK) {
#pragma unroll
        for (int p = 0; p < 4; ++p)
            gload16(gA0 + ((size_t)p * 8 * K + kt) * 2, lA0 + p * 1024);
#pragma unroll
        for (int p = 0; p < 4; ++p)
            gload16(gB0 + ((size_t)p * 8 * K + kt) * 2, lB0 + p * 1024);
        __syncthreads();
#pragma unroll
        for (int kk = 0; kk < BK / 32; ++kk) {
            bf16x8 af[4], bfr[4];
#pragma unroll
            for (int i = 0; i < 4; ++i) {
                int row = wm + i * 16 + l16;
                int byt = (row * 128 + kk * 64 + lhi * 16) ^ ((row & 7) << 4);
                af[i] = *(const bf16x8*)(lds_a + byt);
            }
#pragma unroll
            for (int j = 0; j < 4; ++j) {
                int row = wn + j * 16 + l16;
                int byt = (row * 128 + kk * 64 + lhi * 16) ^ ((row & 7) << 4);
                bfr[j] = *(const bf16x8*)(lds_b + byt);
            }
#pragma unroll
            for (int i = 0; i < 4; ++i)
#pragma unroll
                for (int j = 0; j < 4; ++j)
                    acc[i][j] = __builtin_amdgcn_mfma_f32_16x16x32_bf16(af[i], bfr[j], acc[i][j], 0, 0, 0);
        }
        __syncthreads();
    }

    const size_t obase = (size_t)bz * (size_t)sO;
    if constexpr (!TRANS) {
#pragma unroll
        for (int i = 0; i < 4; ++i) {
            const int m0 = bm + wm + i * 16 + lhi * 4;
#pragma unroll
            for (int j = 0; j < 4; ++j) {
                const int n = bn + wn + j * 16 + l16;
#pragma unroll
                for (int r = 0; r < 4; ++r) {
                    float v = acc[i][j][r];
                    if constexpr (RELU) v = fmaxf(v, 0.f);
                    size_t addr = obase + (size_t)(m0 + r) * N + n;
                    if constexpr (OUT_F32) ((float*)Op)[addr] = v;
                    else ((unsigned short*)Op)[addr] = f2bf(v);
                }
            }
        }
    } else {
#pragma unroll
        for (int i = 0; i < 4; ++i) {
            const int m0 = bm + wm + i * 16 + lhi * 4;
#pragma unroll
            for (int j = 0; j < 4; ++j) {
                const int n = bn + wn + j * 16 + l16;
                u16x4 h;
#pragma unroll
                for (int r = 0; r < 4; ++r) {
                    float v = acc[i][j][r];
                    if constexpr (RELU) v = fmaxf(v, 0.f);
                    h[r] = f2bf(v);
                }
                *(u16x4*)((unsigned short*)Op + obase + (size_t)n * M + m0) = h;
            }
        }
    }
}

// ---------------- 256x256 8-phase kernel (T1+T2+T3+T4+T5) ----------------
// Minimal-LDS-read schedule (round-5): per K-tile each A-half is ds_read once
// (8 x b128) and each B-half once (4 x b128), B halves HELD in regs across the
// two mh phases (b0 used at mm(0,0)/mm(1,0); b1 at mm(0,1)/mm(1,1)).
// 24 KB/wave/K-tile (was 32). Phases 4/8 have no ds_reads -> no lgkmcnt wait.
// Sync skeleton identical to round-4 (race-proven): stage slots at ph1/4/5/8,
// vmcnt(4) gates at ph4/ph8, raw s_barrier pairs per phase.
#define CTILE 65536
#define CBOFF 32768

template<bool OUT_F32, bool TRANS, bool RELU>
__global__ __launch_bounds__(512, 2)
void gemm256(const unsigned short* __restrict__ Ap, const unsigned short* __restrict__ Bp,
             void* __restrict__ Op, int M, int N, int K, int klen, int split,
             long long sA, long long sB, long long sO)
{
    __shared__ char lds[131072];
    const int tid  = threadIdx.x;
    const int wave = tid >> 6;
    const int lane = tid & 63;

    // XCD-aware bijective block swizzle (all grids have nwg % 8 == 0)
    const int gx = gridDim.x, gy = gridDim.y;
    const int f   = blockIdx.x + gx * (blockIdx.y + gy * blockIdx.z);
    const int nwg = gx * gy * (int)gridDim.z;
    const int s   = (f & 7) * (nwg >> 3) + (f >> 3);
    const int lx  = s % gx;
    const int lyz = s / gx;
    const int ly  = lyz % gy;
    const int lz  = lyz / gy;

    const int batch = lz / split;
    const int k0    = (lz % split) * klen;
    const int bm    = ly * 256;
    const int bn    = lx * 256;

    const int wm  = (wave >> 2) * 128;
    const int wn  = (wave & 3) * 64;
    const int l16 = lane & 15, lhi = lane >> 4;

    const unsigned short* Abase = Ap + (size_t)batch * sA + (size_t)bm * K;
    const unsigned short* Bbase = Bp + (size_t)batch * sB + (size_t)bn * K;
    const int srow  = lane >> 3;
    const int schnk = (lane & 7) ^ srow;
    const size_t K2 = (size_t)K * 2;
    const char* gA = (const char*)Abase + (size_t)srow * K2 + (size_t)schnk * 16 + (size_t)k0 * 2;
    const char* gB = (const char*)Bbase + (size_t)srow * K2 + (size_t)schnk * 16 + (size_t)k0 * 2;

    f32x4 acc[8][4];
#pragma unroll
    for (int i = 0; i < 8; ++i)
#pragma unroll
        for (int j = 0; j < 4; ++j)
            acc[i][j] = (f32x4){0.f, 0.f, 0.f, 0.f};

    bf16x8 a[4][2], b0[2][2], b1[2][2];

    auto stageA = [&](int c, int t) {
#pragma unroll
        for (int h = 0; h < 2; ++h)
#pragma unroll
            for (int p = 0; p < 2; ++p)
                gload16(gA + (size_t)t * 128 + (size_t)(h * 128 + wave * 16 + p * 8) * K2,
                        lds + c * CTILE + h * 16384 + wave * 2048 + p * 1024);
    };
    auto stageB = [&](int c, int t) {
#pragma unroll
        for (int h = 0; h < 2; ++h)
#pragma unroll
            for (int p = 0; p < 2; ++p)
                gload16(gB + (size_t)t * 128 + (size_t)(h * 128 + wave * 16 + p * 8) * K2,
                        lds + c * CTILE + CBOFF + h * 16384 + wave * 2048 + p * 1024);
    };
    auto ldA = [&](int c, int mh) {
#pragma unroll
        for (int i4 = 0; i4 < 4; ++i4)
#pragma unroll
            for (int kk = 0; kk < 2; ++kk) {
                int row = wm + mh * 64 + i4 * 16 + l16;
                int byt = (row * 128 + kk * 64 + lhi * 16) ^ ((row & 7) << 4);
                a[i4][kk] = *(const bf16x8*)(lds + c * CTILE + byt);
            }
    };
    auto ldB = [&](int c, int nh, bf16x8 (&bb)[2][2]) {
#pragma unroll
        for (int j2 = 0; j2 < 2; ++j2)
#pragma unroll
            for (int kk = 0; kk < 2; ++kk) {
                int row = wn + nh * 32 + j2 * 16 + l16;
                int byt = (row * 128 + kk * 64 + lhi * 16) ^ ((row & 7) << 4);
                bb[j2][kk] = *(const bf16x8*)(lds + c * CTILE + CBOFF + byt);
            }
    };
    auto mm = [&](int mh, int nh, bf16x8 (&bb)[2][2]) {
        __builtin_amdgcn_s_setprio(1);
#pragma unroll
        for (int i4 = 0; i4 < 4; ++i4)
#pragma unroll
            for (int j2 = 0; j2 < 2; ++j2)
#pragma unroll
                for (int kk = 0; kk < 2; ++kk)
                    acc[mh * 4 + i4][nh * 2 + j2] = __builtin_amdgcn_mfma_f32_16x16x32_bf16(
                        a[i4][kk], bb[j2][kk], acc[mh * 4 + i4][nh * 2 + j2], 0, 0, 0);
        __builtin_amdgcn_s_setprio(0);
    };

#define BAR()  __builtin_amdgcn_s_barrier()
#define LGKM0() asm volatile("s_waitcnt lgkmcnt(0)" ::: "memory")
#define VM4()  asm volatile("s_waitcnt vmcnt(4)" ::: "memory")

    const int NT = klen / 64;
    stageA(0, 0); stageB(0, 0); stageA(1, 1);
    VM4();
    BAR();

    for (int itr = 0; itr < NT / 2; ++itr) {
        const int t1  = 2 * itr + 1;
        const int tp0 = (2 * itr + 2) % NT;
        const int tp1 = (2 * itr + 3) % NT;
        // ph1
        ldA(0, 0); ldB(0, 0, b0); stageB(1, t1);
        BAR(); LGKM0(); mm(0, 0, b0); BAR();
        // ph2
        ldB(0, 1, b1);
        BAR(); LGKM0(); mm(0, 1, b1); BAR();
        // ph3
        ldA(0, 1);
        BAR(); LGKM0(); mm(1, 0, b0); BAR();
        // ph4 (no ds_reads)
        stageA(0, tp0);
        BAR(); mm(1, 1, b1); VM4(); BAR();
        // ph5
        ldA(1, 0); ldB(1, 0, b0); stageB(0, tp0);
        BAR(); LGKM0(); mm(0, 0, b0); BAR();
        // ph6
        ldB(1, 1, b1);
        BAR(); LGKM0(); mm(0, 1, b1); BAR();
        // ph7
        ldA(1, 1);
        BAR(); LGKM0(); mm(1, 0, b0); BAR();
        // ph8 (no ds_reads)
        stageA(1, tp1);
        BAR(); mm(1, 1, b1); VM4(); BAR();
    }
    asm volatile("s_waitcnt vmcnt(0)" ::: "memory");

    const size_t obase = (size_t)lz * (size_t)sO;
    if constexpr (!TRANS) {
#pragma unroll
        for (int i = 0; i < 8; ++i) {
            const int m0 = bm + wm + i * 16 + lhi * 4;
#pragma unroll
            for (int j = 0; j < 4; ++j) {
                const int n = bn + wn + j * 16 + l16;
#pragma unroll
                for (int r = 0; r < 4; ++r) {
                    float v = acc[i][j][r];
                    if constexpr (RELU) v = fmaxf(v, 0.f);
                    size_t addr = obase + (size_t)(m0 + r) * N + n;
                    if constexpr (OUT_F32) ((float*)Op)[addr] = v;
                    else ((unsigned short*)Op)[addr] = f2bf(v);
                }
            }
        }
    } else {
#pragma unroll
        for (int i = 0; i < 8; ++i) {
            const int m0 = bm + wm + i * 16 + lhi * 4;
#pragma unroll
            for (int j = 0; j < 4; ++j) {
                const int n = bn + wn + j * 16 + l16;
                u16x4 h;
#pragma unroll
                for (int r = 0; r < 4; ++r) {
                    float v = acc[i][j][r];
                    if constexpr (RELU) v = fmaxf(v, 0.f);
                    h[r] = f2bf(v);
                }
                *(u16x4*)((unsigned short*)Op + obase + (size_t)n * M + m0) = h;
            }
        }
    }
#undef BAR
#undef LGKM0
#undef VM4
}

extern "C" void kernel_launch(void* const* d_in, const int* in_sizes, int n_in,
                              void* d_out, int out_size, void* d_ws, size_t ws_size,
                              hipStream_t stream) {
    (void)in_sizes; (void)n_in; (void)out_size;
    const float* x  = (const float*)d_in[0];
    const float* Wa = (const float*)d_in[1];
    const float* Wb = (const float*)d_in[2];
    const float* Wc = (const float*)d_in[3];
    const float* Wd = (const float*)d_in[4];

    const long long SD  = (long long)S_ * D_;
    const long long DD2 = (long long)D_ * D_;
    const size_t MB = 1024 * 1024;

    unsigned short* r0 = (unsigned short*)d_ws;
    unsigned short* r1 = (unsigned short*)((char*)d_ws + 32 * MB);
    unsigned short* Ft = r1;
    const bool big_ws = ws_size >= (size_t)96 * MB;

    char* ob = (char*)d_out;
    unsigned short* xb    = (unsigned short*)ob;
    unsigned short* Pp    = big_ws ? (unsigned short*)((char*)d_ws + 64 * MB)
                                   : (unsigned short*)(ob + 32 * MB);
    unsigned short* Enorm = (unsigned short*)(ob + 48 * MB);
    unsigned short* Wbb   = (unsigned short*)(ob + 56 * MB);
    unsigned short* Wcb   = (unsigned short*)(ob + 58 * MB);
    unsigned short* Wab   = (unsigned short*)(ob + 60 * MB);
    unsigned short* Wdb   = (unsigned short*)(ob + 62 * MB);
    const int esplit = big_ws ? 4 : 2;
    const int eklen  = S_ / esplit;

    dim3 blk256(256, 1, 1);
    dim3 blk512(512, 1, 1);
    dim3 gS(D_ / 256, S_ / 256, B_);          // (4,16,4) = 256 blocks
    dim3 gE(D_ / 256, D_ / 256, B_ * esplit); // (4,4,16) or (4,4,8)
    dim3 gF(D_ / BN, D_ / BM, B_);            // (8,8,4)

    // 0) bf16-ify inputs (weights in ONE launch)
    conv_bf16<<<2048, blk256, 0, stream>>>(x, xb, (B_ * S_ * D_) / 8);
    conv_bf16_w4<<<1024, blk256, 0, stream>>>(Wb, Wc, Wa, Wd, Wbb, Wcb, Wab, Wdb, (D_ * D_) / 8);

    // 1) Bmt[b][e][s] = relu(xb Wb^T)^T  -> r0
    gemm256<false, true,  true ><<<gS, blk512, 0, stream>>>(xb, Wbb, r0, S_, D_, D_, D_, 1, SD, 0, SD);
    // 2) Ct[b][e][s]  = relu(xb Wc^T)^T  -> r1
    gemm256<false, true,  true ><<<gS, blk512, 0, stream>>>(xb, Wcb, r1, S_, D_, D_, D_, 1, SD, 0, SD);
    // 3) E2 partials
    gemm256<false, false, false><<<gE, blk512, 0, stream>>>(r0, r1, Pp, D_, D_, S_, eklen, esplit, SD, SD, DD2);
    // 3b) Enorm[b] = sum_seg P
    reduceN_bf16<<<2048, blk256, 0, stream>>>(Pp, Enorm, esplit, (B_ * D_ * D_) / 8);
    // 3c) Ft = (E2 @ Wd^T)^T -> r1 (Ct dead)
    gemm_nt<false, true,  false><<<gF, blk256, 0, stream>>>(Enorm, Wdb, Ft, D_, D_, D_, D_, 1, DD2, 0, DD2);
    // 4) A = relu(xb Wa^T) -> r0 (Bmt dead)
    gemm256<false, false, true ><<<gS, blk512, 0, stream>>>(xb, Wab, r0, S_, D_, D_, D_, 1, SD, 0, SD);
    // 5) out = relu(A @ Ft-rows) f32 -> d_out
    gemm256<true,  false, true ><<<gS, blk512, 0, stream>>>(r0, Ft, (float*)d_out, S_, D_, D_, D_, 1, SD, DD2, SD);
}